// Round 10
// baseline (33.059 us; speedup 1.0000x reference)
//
#include <hip/hip_runtime.h>

#define EPSV 2.220446049250313e-16f
#define C3F  (-0.09016844005555896f)   // -log2(e)/16
#define SSCL 0.1201122408786449f       // sqrt(log2(e)/100); (SSCL*dI)^2 = dI^2*log2(e)/100
#define EPSS (EPSV * SSCL)

typedef float f2 __attribute__((ext_vector_type(2)));
typedef float f4 __attribute__((ext_vector_type(4)));

// Half-space (pair-symmetry) formulation, R9-verified algebra:
//   acc_k(p) = sum_{o in H} w(p,p+o) * Ppad_k(p+o)      (125 in-ball offsets total)
//   W(p)     = sum_{o in H} w(p,p+o)
//   A_k = sum_p [ 2*P_k(p)*acc_k(p) + P_k(p)^2 ]                      (+O(eps))
//   V_k = sum_p [ P_k(p)*(W(p) + e(p)*S(p) + 1) + acc_k(p) ]          (+O(eps))
// e(p)=exp2(-(s*I(p)-s*eps)^2), S(p)=sum_{o in H: p-o outside grid} dist(o).
// Grid: (oz,b,d) = 4*8*32 = 1024 blocks, 512 threads, 2 voxels/thread.
// 8 waves/block x 4 blocks/CU (40KB LDS) -> up to 32 waves/CU. LS=38 conflict-free.

__global__ __launch_bounds__(512) void ncut_main(const float* __restrict__ batch,
                                                 const float* __restrict__ preds,
                                                 float* __restrict__ wsA,
                                                 float* __restrict__ wsV) {
    constexpr int LS = 38;             // LDS row stride (floats)
    constexpr int PLANE = 38 * LS;     // 1444 floats per padded slice
    __shared__ float sAll[7 * PLANE];  // plane 0: scaled batch; planes 1..6: preds
    __shared__ float redBuf[8][12];

    const int tid = threadIdx.x;
    const int bx  = blockIdx.x;
    const int oz  = bx >> 8;           // 0..3 (slowest-varying: balances CU load)
    const int b   = (bx >> 5) & 7;     // batch
    const int d   = bx & 31;           // center z-slice

    const int z   = d + oz;            // partner slice (never <0)
    const bool zok = (z < 32);

    // ---- init planes to pad value (7*1444/4 = 2527 f4) ----
    {
        f4* a4 = (f4*)sAll;
        const f4 bpad = {EPSS, EPSS, EPSS, EPSS};
        const f4 ppad = {EPSV, EPSV, EPSV, EPSV};
        for (int i = tid; i < 2527; i += 512) a4[i] = (i < 361) ? bpad : ppad;
    }
    __syncthreads();

    // ---- copy interiors: coalesced f4 loads (1792 = 7 planes * 256 tiles) ----
    if (zok) {
        const float* bsrc = batch + ((size_t)b * 32 + z) * 1024;
        const float* psrc = preds + ((size_t)b * 6 * 32 + z) * 1024;
        #pragma unroll
        for (int it = 0; it < 4; ++it) {
            int idx = tid + it * 512;
            if (idx < 1792) {
                int p  = idx >> 8;             // 0..6
                int r8 = idx & 255;
                int hh = r8 >> 3;              // 0..31
                int j4 = (r8 & 7) << 2;        // 0,4,...,28
                const float* src = (p == 0) ? (bsrc + hh * 32 + j4)
                                            : (psrc + (size_t)(p - 1) * 32768 + hh * 32 + j4);
                f4 v = *(const f4*)src;
                if (p == 0) v *= SSCL;
                float* dst = sAll + p * PLANE + (hh + 3) * LS + (j4 + 3);
                dst[0] = v.x; dst[1] = v.y; dst[2] = v.z; dst[3] = v.w;
            }
        }
    }

    // compute mapping: 2 voxels per thread
    const int h  = (tid >> 4) & 31;    // row
    const int v0 = (tid & 15) << 1;    // voxel start (even)
    f2 Ip = *(const f2*)&batch[((size_t)b * 32 + d) * 1024 + h * 32 + v0];
    Ip *= SSCL;

    __syncthreads();

    f2 wsum = {};
    f2 acc[6] = {};
    const int czz = oz * oz;
    const float gz = (float)czz * C3F;

    #pragma unroll
    for (int dy = 0; dy < 7; ++dy) {
        const int oy  = dy - 3;
        const int cyy = oy * oy;                  // compile-time
        if (czz + cyy >= 16) continue;            // scalar: outside ball
        if (oz == 0 && oy < 0) continue;          // scalar: lex-negative rows

        const int rowOff = (h + dy) * LS + v0;    // even -> 8B aligned
        const f2* br = (const f2*)(sAll + rowOff);
        f2 t0 = br[0], t1 = br[1], t2 = br[2], t3 = br[3];
        float bseg[8] = {t0.x, t0.y, t1.x, t1.y, t2.x, t2.y, t3.x, t3.y};

        f2 wv[7] = {};
        #pragma unroll
        for (int dx = 0; dx < 7; ++dx) {
            const int ox  = dx - 3;
            const int cxx = ox * ox;              // compile-time
            if (czz + cyy + cxx < 16 && !(oz == 0 && oy == 0 && ox <= 0)) {
                const float g = gz + (float)(cyy + cxx) * C3F;
                f2 bv = {bseg[dx], bseg[dx + 1]};
                f2 dI = Ip - bv;
                f2 t  = (f2){g, g} - dI * dI;
                f2 w;
                w.x = __builtin_amdgcn_exp2f(t.x);
                w.y = __builtin_amdgcn_exp2f(t.y);
                wv[dx] = w;
                wsum += w;
            }
        }

        #pragma unroll
        for (int k = 0; k < 6; ++k) {
            const f2* pr = (const f2*)(sAll + (k + 1) * PLANE + rowOff);
            f2 q0 = pr[0], q1 = pr[1], q2 = pr[2], q3 = pr[3];
            float pseg[8] = {q0.x, q0.y, q1.x, q1.y, q2.x, q2.y, q3.x, q3.y};
            f2 a = acc[k];
            #pragma unroll
            for (int dx = 0; dx < 7; ++dx) {
                const int ox  = dx - 3;
                const int cxx = ox * ox;
                if (czz + cyy + cxx < 16 && !(oz == 0 && oy == 0 && ox <= 0))
                    a += wv[dx] * (f2){pseg[dx], pseg[dx + 1]};
            }
            acc[k] = a;
        }
    }

    // ---- reverse-direction pad correction: S(p) = sum dist over o in H with p-o outside grid ----
    f2 S = {};
    if ((d < oz) || (h < 3) || (h > 28) || (v0 <= 2) || (v0 >= 28)) {
        const float edz = __builtin_amdgcn_exp2f(gz);   // exp2(czz*C3F)
        #pragma unroll
        for (int oy = -3; oy <= 3; ++oy) {
            #pragma unroll
            for (int ox = -3; ox <= 3; ++ox) {
                const int d2c = oy * oy + ox * ox;
                if (czz + d2c >= 16) continue;                              // scalar
                if (oz == 0 && (oy < 0 || (oy == 0 && ox <= 0))) continue;  // scalar lex
                const float dist = edz * __builtin_exp2f((float)d2c * C3F); // const-folded
                const bool sc = (d < oz) || (h < oy) || (h > 31 + oy);
                #pragma unroll
                for (int j = 0; j < 2; ++j) {
                    const int xj = v0 + j;
                    bool m = sc;
                    if (ox > 0) m = m || (xj < ox);        // folds unless ox>0
                    if (ox < 0) m = m || (xj > 31 + ox);   // folds unless ox<0
                    S[j] += m ? dist : 0.0f;
                }
            }
        }
    }
    // e(p) = exp2(-(sI - s*eps)^2); fold correction into wsum before the center dot
    {
        f2 dIe = Ip - (f2){EPSS, EPSS};
        f2 e2;
        e2.x = __builtin_amdgcn_exp2f(-dIe.x * dIe.x);
        e2.y = __builtin_amdgcn_exp2f(-dIe.y * dIe.y);
        wsum += e2 * S;
    }

    // ---- epilogue: per-class partials ----
    float pA[6], pV[6];
    #pragma unroll
    for (int k = 0; k < 6; ++k) {
        const size_t pc = (((size_t)b * 6 + k) * 32 + d) * 1024 + h * 32 + v0;
        f2 pcv = *(const f2*)&preds[pc];
        float dA = acc[k].x * pcv.x + acc[k].y * pcv.y;
        float hA = acc[k].x + acc[k].y;
        float dV = wsum.x * pcv.x + wsum.y * pcv.y;
        pA[k] = 2.0f * dA;
        pV[k] = dV + hA;
        if (oz == 0) {   // o=0 term: A += P^2, V += P (once per (b,d))
            pA[k] += pcv.x * pcv.x + pcv.y * pcv.y;
            pV[k] += pcv.x + pcv.y;
        }
    }

    // wave reduction (64 lanes)
    #pragma unroll
    for (int k = 0; k < 6; ++k) {
        #pragma unroll
        for (int off = 32; off > 0; off >>= 1) {
            pA[k] += __shfl_down(pA[k], off);
            pV[k] += __shfl_down(pV[k], off);
        }
    }
    const int lane = tid & 63, wave = tid >> 6;
    if (lane == 0) {
        #pragma unroll
        for (int k = 0; k < 6; ++k) {
            redBuf[wave][k]     = pA[k];
            redBuf[wave][6 + k] = pV[k];
        }
    }
    __syncthreads();
    if (tid < 12) {
        float s = 0.f;
        #pragma unroll
        for (int wv8 = 0; wv8 < 8; ++wv8) s += redBuf[wv8][tid];
        if (tid < 6) wsA[bx * 6 + tid] = s;
        else         wsV[bx * 6 + (tid - 6)] = s;
    }
}

// Reduce 128 partials per batch (4 oz * 32 d), form 6 - sum_k A_k/V_k
__global__ __launch_bounds__(128) void ncut_final(const float* __restrict__ wsA,
                                                  const float* __restrict__ wsV,
                                                  float* __restrict__ out) {
    __shared__ float redBuf[2][12];
    const int b = blockIdx.x;
    const int t = threadIdx.x;            // 0..127 = (oz, d)
    const int oz = t >> 5, dd = t & 31;
    const int bx = oz * 256 + b * 32 + dd;
    float a[6], v[6];
    #pragma unroll
    for (int k = 0; k < 6; ++k) {
        a[k] = wsA[(size_t)bx * 6 + k];
        v[k] = wsV[(size_t)bx * 6 + k];
    }
    #pragma unroll
    for (int k = 0; k < 6; ++k) {
        #pragma unroll
        for (int off = 32; off > 0; off >>= 1) {
            a[k] += __shfl_down(a[k], off);
            v[k] += __shfl_down(v[k], off);
        }
    }
    const int lane = t & 63, wave = t >> 6;
    if (lane == 0) {
        #pragma unroll
        for (int k = 0; k < 6; ++k) {
            redBuf[wave][k]     = a[k];
            redBuf[wave][6 + k] = v[k];
        }
    }
    __syncthreads();
    if (t == 0) {
        float s = 0.f;
        #pragma unroll
        for (int k = 0; k < 6; ++k) {
            float sa = redBuf[0][k] + redBuf[1][k];
            float sv = redBuf[0][6 + k] + redBuf[1][6 + k];
            s += sa / sv;
        }
        out[b] = 6.0f - s;
    }
}

extern "C" void kernel_launch(void* const* d_in, const int* in_sizes, int n_in,
                              void* d_out, int out_size, void* d_ws, size_t ws_size,
                              hipStream_t stream) {
    const float* batch = (const float*)d_in[0];   // 8*1*32^3
    const float* preds = (const float*)d_in[1];   // 8*6*32^3
    float* out = (float*)d_out;                   // 8 floats
    float* wsA = (float*)d_ws;                    // 1024*6 floats
    float* wsV = wsA + 1024 * 6;                  // 1024*6 floats

    ncut_main<<<1024, 512, 0, stream>>>(batch, preds, wsA, wsV);
    ncut_final<<<8, 128, 0, stream>>>(wsA, wsV, out);
}

// Round 11
// 30.514 us; speedup vs baseline: 1.0834x; 1.0834x over previous
//
#include <hip/hip_runtime.h>

#define EPSV 2.220446049250313e-16f
#define C3F  (-0.09016844005555896f)   // -log2(e)/16
#define SSCL 0.1201122408786449f       // sqrt(log2(e)/100); (SSCL*dI)^2 = dI^2*log2(e)/100
#define EPSS (EPSV * SSCL)

typedef float f2 __attribute__((ext_vector_type(2)));
typedef float f4 __attribute__((ext_vector_type(4)));

// Half-space (pair-symmetry) formulation, R9-verified algebra:
//   acc_k(p) = sum_{o in H} w(p,p+o) * Ppad_k(p+o)      (125 in-ball offsets)
//   A_k = sum_p [ 2*P_k(p)*acc_k(p) + P_k(p)^2 ]
//   V_k = sum_p [ P_k(p)*(W(p) + e(p)*S(p) + 1) + acc_k(p) ]
// Grid: (oz,b,d) = 4*8*32 = 1024 blocks, 256 threads, 4 voxels/thread.
// R11: software-pipelined inner loop — pseg(k+1) prefetched into named regs
// while FMA-ing pseg(k); bseg+pseg(0) issued together so the weight/exp chain
// covers the first pseg latency. LS=38 conflict-free b64 (R7-verified).

__global__ __launch_bounds__(256) void ncut_main(const float* __restrict__ batch,
                                                 const float* __restrict__ preds,
                                                 float* __restrict__ wsA,
                                                 float* __restrict__ wsV) {
    constexpr int LS = 38;             // LDS row stride (floats)
    constexpr int PLANE = 38 * LS;     // 1444 floats per padded slice
    __shared__ float sAll[7 * PLANE];  // plane 0: scaled batch; planes 1..6: preds
    __shared__ float redBuf[4][12];

    const int tid = threadIdx.x;
    const int bx  = blockIdx.x;
    const int oz  = bx >> 8;           // 0..3 (slowest-varying: balances CU load)
    const int b   = (bx >> 5) & 7;     // batch
    const int d   = bx & 31;           // center z-slice

    const int z   = d + oz;            // partner slice (never <0)
    const bool zok = (z < 32);

    // ---- init planes to pad value (7*1444/4 = 2527 f4) ----
    {
        f4* a4 = (f4*)sAll;
        const f4 bpad = {EPSS, EPSS, EPSS, EPSS};
        const f4 ppad = {EPSV, EPSV, EPSV, EPSV};
        for (int i = tid; i < 2527; i += 256) a4[i] = (i < 361) ? bpad : ppad;
    }
    __syncthreads();

    // ---- copy interiors: coalesced f4 loads ----
    const int hh = tid >> 3;           // 0..31
    const int j4 = (tid & 7) << 2;     // 0,4,...,28
    if (zok) {
        const float* bsrc = batch + ((size_t)b * 32 + z) * 1024 + hh * 32 + j4;
        const float* psrc = preds + ((size_t)b * 6 * 32 + z) * 1024 + hh * 32 + j4;
        {
            f4 v = *(const f4*)bsrc;
            v *= SSCL;
            float* dst = sAll + (hh + 3) * LS + (j4 + 3);
            dst[0] = v.x; dst[1] = v.y; dst[2] = v.z; dst[3] = v.w;
        }
        #pragma unroll
        for (int p = 0; p < 6; ++p) {
            f4 v = *(const f4*)(psrc + (size_t)p * 32768);
            float* dst = sAll + (p + 1) * PLANE + (hh + 3) * LS + (j4 + 3);
            dst[0] = v.x; dst[1] = v.y; dst[2] = v.z; dst[3] = v.w;
        }
    }

    const int h  = hh;                 // row
    const int v0 = j4;                 // voxel start
    f4 Ip = *(const f4*)&batch[((size_t)b * 32 + d) * 1024 + h * 32 + v0];
    Ip *= SSCL;

    __syncthreads();

    f4 wsum = {};
    f4 acc[6] = {};
    const int czz = oz * oz;
    const float gz = (float)czz * C3F;

    #pragma unroll
    for (int dy = 0; dy < 7; ++dy) {
        const int oy  = dy - 3;
        const int cyy = oy * oy;                  // compile-time
        if (czz + cyy >= 16) continue;            // scalar: outside ball
        if (oz == 0 && oy < 0) continue;          // scalar: lex-negative rows

        const int rowOff = (h + dy) * LS + v0;    // even -> 8B aligned
        const f2* base = (const f2*)(sAll + rowOff);
        constexpr int PL2 = PLANE / 2;            // f2 stride per plane

        // issue bseg AND pseg(k=0) together: weight chain hides pseg(0) latency
        f2 tb0 = base[0], tb1 = base[1], tb2 = base[2], tb3 = base[3], tb4 = base[4];
        f2 c0 = base[PL2 + 0], c1 = base[PL2 + 1], c2 = base[PL2 + 2],
           c3 = base[PL2 + 3], c4 = base[PL2 + 4];

        float bseg[10] = {tb0.x, tb0.y, tb1.x, tb1.y, tb2.x, tb2.y, tb3.x, tb3.y, tb4.x, tb4.y};

        f4 wv[7] = {};
        #pragma unroll
        for (int dx = 0; dx < 7; ++dx) {
            const int ox  = dx - 3;
            const int cxx = ox * ox;              // compile-time
            if (czz + cyy + cxx < 16 && !(oz == 0 && oy == 0 && ox <= 0)) {
                const float g = gz + (float)(cyy + cxx) * C3F;
                f4 bv = {bseg[dx], bseg[dx + 1], bseg[dx + 2], bseg[dx + 3]};
                f4 dI = Ip - bv;
                f4 t  = (f4){g, g, g, g} - dI * dI;
                f4 w;
                w.x = __builtin_amdgcn_exp2f(t.x);
                w.y = __builtin_amdgcn_exp2f(t.y);
                w.z = __builtin_amdgcn_exp2f(t.z);
                w.w = __builtin_amdgcn_exp2f(t.w);
                wv[dx] = w;
                wsum += w;
            }
        }

        // k-loop, 2-stage pipelined: prefetch pseg(k+1) before FMA-ing pseg(k)
        #pragma unroll
        for (int k = 0; k < 6; ++k) {
            f2 n0, n1, n2, n3, n4;
            if (k < 5) {
                const f2* nb = base + (size_t)(k + 2) * PL2;
                n0 = nb[0]; n1 = nb[1]; n2 = nb[2]; n3 = nb[3]; n4 = nb[4];
            }
            float pseg[10] = {c0.x, c0.y, c1.x, c1.y, c2.x, c2.y, c3.x, c3.y, c4.x, c4.y};
            f4 a = acc[k];
            #pragma unroll
            for (int dx = 0; dx < 7; ++dx) {
                const int ox  = dx - 3;
                const int cxx = ox * ox;
                if (czz + cyy + cxx < 16 && !(oz == 0 && oy == 0 && ox <= 0))
                    a += wv[dx] * (f4){pseg[dx], pseg[dx + 1], pseg[dx + 2], pseg[dx + 3]};
            }
            acc[k] = a;
            if (k < 5) { c0 = n0; c1 = n1; c2 = n2; c3 = n3; c4 = n4; }
        }
    }

    // ---- reverse-direction pad correction: S(p) = sum dist over o in H with p-o outside grid ----
    f4 S = {};
    if ((d < oz) || (h < 3) || (h > 28) || (v0 == 0) || (v0 == 28)) {
        const float edz = __builtin_amdgcn_exp2f(gz);   // exp2(czz*C3F)
        #pragma unroll
        for (int oy = -3; oy <= 3; ++oy) {
            #pragma unroll
            for (int ox = -3; ox <= 3; ++ox) {
                const int d2c = oy * oy + ox * ox;
                if (czz + d2c >= 16) continue;                              // scalar
                if (oz == 0 && (oy < 0 || (oy == 0 && ox <= 0))) continue;  // scalar lex
                const float dist = edz * __builtin_exp2f((float)d2c * C3F); // const-folded
                const bool sc = (d < oz) || (h < oy) || (h > 31 + oy);
                #pragma unroll
                for (int j = 0; j < 4; ++j) {
                    const int xj = v0 + j;
                    bool m = sc;
                    if (ox > 0) m = m || (xj < ox);        // folds unless ox>0
                    if (ox < 0) m = m || (xj > 31 + ox);   // folds unless ox<0
                    S[j] += m ? dist : 0.0f;
                }
            }
        }
    }
    // e(p) = exp2(-(sI - s*eps)^2); fold correction into wsum before the center dot
    {
        f4 dIe = Ip - (f4){EPSS, EPSS, EPSS, EPSS};
        f4 e4;
        e4.x = __builtin_amdgcn_exp2f(-dIe.x * dIe.x);
        e4.y = __builtin_amdgcn_exp2f(-dIe.y * dIe.y);
        e4.z = __builtin_amdgcn_exp2f(-dIe.z * dIe.z);
        e4.w = __builtin_amdgcn_exp2f(-dIe.w * dIe.w);
        wsum += e4 * S;
    }

    // ---- epilogue: per-class partials ----
    float pA[6], pV[6];
    #pragma unroll
    for (int k = 0; k < 6; ++k) {
        const size_t pc = (((size_t)b * 6 + k) * 32 + d) * 1024 + h * 32 + v0;
        f4 pcv = *(const f4*)&preds[pc];
        float dA = acc[k].x * pcv.x + acc[k].y * pcv.y + acc[k].z * pcv.z + acc[k].w * pcv.w;
        float hA = acc[k].x + acc[k].y + acc[k].z + acc[k].w;
        float dV = wsum.x * pcv.x + wsum.y * pcv.y + wsum.z * pcv.z + wsum.w * pcv.w;
        pA[k] = 2.0f * dA;
        pV[k] = dV + hA;
        if (oz == 0) {   // o=0 term: A += P^2, V += P (once per (b,d))
            pA[k] += pcv.x * pcv.x + pcv.y * pcv.y + pcv.z * pcv.z + pcv.w * pcv.w;
            pV[k] += pcv.x + pcv.y + pcv.z + pcv.w;
        }
    }

    // wave reduction (64 lanes)
    #pragma unroll
    for (int k = 0; k < 6; ++k) {
        #pragma unroll
        for (int off = 32; off > 0; off >>= 1) {
            pA[k] += __shfl_down(pA[k], off);
            pV[k] += __shfl_down(pV[k], off);
        }
    }
    const int lane = tid & 63, wave = tid >> 6;
    if (lane == 0) {
        #pragma unroll
        for (int k = 0; k < 6; ++k) {
            redBuf[wave][k]     = pA[k];
            redBuf[wave][6 + k] = pV[k];
        }
    }
    __syncthreads();
    if (tid < 12) {
        float s = redBuf[0][tid] + redBuf[1][tid] + redBuf[2][tid] + redBuf[3][tid];
        if (tid < 6) wsA[bx * 6 + tid] = s;
        else         wsV[bx * 6 + (tid - 6)] = s;
    }
}

// Reduce 128 partials per batch (4 oz * 32 d), form 6 - sum_k A_k/V_k
__global__ __launch_bounds__(128) void ncut_final(const float* __restrict__ wsA,
                                                  const float* __restrict__ wsV,
                                                  float* __restrict__ out) {
    __shared__ float redBuf[2][12];
    const int b = blockIdx.x;
    const int t = threadIdx.x;            // 0..127 = (oz, d)
    const int oz = t >> 5, dd = t & 31;
    const int bx = oz * 256 + b * 32 + dd;
    float a[6], v[6];
    #pragma unroll
    for (int k = 0; k < 6; ++k) {
        a[k] = wsA[(size_t)bx * 6 + k];
        v[k] = wsV[(size_t)bx * 6 + k];
    }
    #pragma unroll
    for (int k = 0; k < 6; ++k) {
        #pragma unroll
        for (int off = 32; off > 0; off >>= 1) {
            a[k] += __shfl_down(a[k], off);
            v[k] += __shfl_down(v[k], off);
        }
    }
    const int lane = t & 63, wave = t >> 6;
    if (lane == 0) {
        #pragma unroll
        for (int k = 0; k < 6; ++k) {
            redBuf[wave][k]     = a[k];
            redBuf[wave][6 + k] = v[k];
        }
    }
    __syncthreads();
    if (t == 0) {
        float s = 0.f;
        #pragma unroll
        for (int k = 0; k < 6; ++k) {
            float sa = redBuf[0][k] + redBuf[1][k];
            float sv = redBuf[0][6 + k] + redBuf[1][6 + k];
            s += sa / sv;
        }
        out[b] = 6.0f - s;
    }
}

extern "C" void kernel_launch(void* const* d_in, const int* in_sizes, int n_in,
                              void* d_out, int out_size, void* d_ws, size_t ws_size,
                              hipStream_t stream) {
    const float* batch = (const float*)d_in[0];   // 8*1*32^3
    const float* preds = (const float*)d_in[1];   // 8*6*32^3
    float* out = (float*)d_out;                   // 8 floats
    float* wsA = (float*)d_ws;                    // 1024*6 floats
    float* wsV = wsA + 1024 * 6;                  // 1024*6 floats

    ncut_main<<<1024, 256, 0, stream>>>(batch, preds, wsA, wsV);
    ncut_final<<<8, 128, 0, stream>>>(wsA, wsV, out);
}